// Round 18
// baseline (640.699 us; speedup 1.0000x reference)
//
#include <hip/hip_runtime.h>
#include <hip/hip_bf16.h>
#include <cstdint>

#define M_DIM 8192
#define K_DIM 4096
#define N_DIM 11008
#define NGROUPS 32

typedef __attribute__((ext_vector_type(4))) float f32x4;
typedef __attribute__((ext_vector_type(4))) int i32x4;
typedef __attribute__((ext_vector_type(16))) int i32x16;
typedef __attribute__((ext_vector_type(8))) __bf16 bf16x8;

__device__ __forceinline__ unsigned int f2bf(float f) {
  unsigned int u = __builtin_bit_cast(unsigned int, f);
  return (u + 0x7FFFu + ((u >> 16) & 1u)) >> 16;
}
__device__ __forceinline__ unsigned int pk2(float lo, float hi) {
  return f2bf(lo) | (f2bf(hi) << 16);
}

// ---- prepass A: per-row int8 quantization, single-pass (regs), nt loads ----
__global__ __launch_bounds__(256) void quantA_kernel(const float* __restrict__ in,
                                                     char* __restrict__ outA,
                                                     float* __restrict__ sA) {
  const int row = blockIdx.x * 4 + (threadIdx.x >> 6);
  const int lane = threadIdx.x & 63;
  const f32x4* p4 = (const f32x4*)(in + (size_t)row * K_DIM);
  f32x4 v[16];
#pragma unroll
  for (int e = 0; e < 16; ++e)
    v[e] = __builtin_nontemporal_load(&p4[e * 64 + lane]);
  float mx = 0.f;
#pragma unroll
  for (int e = 0; e < 16; ++e)
    mx = fmaxf(mx, fmaxf(fmaxf(fabsf(v[e].x), fabsf(v[e].y)),
                         fmaxf(fabsf(v[e].z), fabsf(v[e].w))));
#pragma unroll
  for (int off = 32; off; off >>= 1) mx = fmaxf(mx, __shfl_xor(mx, off));
  mx = fmaxf(mx, 1e-30f);
  const float rq = 127.f / mx;
  if (lane == 0) sA[row] = mx / 127.f;
  char* op = outA + (size_t)row * K_DIM;
#pragma unroll
  for (int e = 0; e < 16; ++e) {
    unsigned pk = ((unsigned)((int)rintf(v[e].x * rq)) & 0xFFu)
                | (((unsigned)((int)rintf(v[e].y * rq)) & 0xFFu) << 8)
                | (((unsigned)((int)rintf(v[e].z * rq)) & 0xFFu) << 16)
                | (((unsigned)((int)rintf(v[e].w * rq)) & 0xFFu) << 24);
    *(unsigned*)(op + e * 256 + lane * 4) = pk;
  }
}

// ---- prepass W: per-column int8 re-quant, single-pass (regs), nt loads ----
__global__ __launch_bounds__(256) void quantW_kernel(const int* __restrict__ wc,
                                                     const float* __restrict__ sc,
                                                     char* __restrict__ outB,
                                                     float* __restrict__ sW) {
  const int col = blockIdx.x * 4 + (threadIdx.x >> 6);
  const int lane = threadIdx.x & 63;
  const i32x4* p = (const i32x4*)(wc + (size_t)col * K_DIM);
  const float* scp = sc + col * NGROUPS;
  i32x4 c[16];
  float s[16];
#pragma unroll
  for (int e = 0; e < 16; ++e) {
    c[e] = __builtin_nontemporal_load(&p[e * 64 + lane]);
    s[e] = scp[e * 2 + (lane >> 5)];
  }
  float mx = 0.f;
#pragma unroll
  for (int e = 0; e < 16; ++e) {
    float m = fmaxf(fmaxf(fabsf((float)c[e].x), fabsf((float)c[e].y)),
                    fmaxf(fabsf((float)c[e].z), fabsf((float)c[e].w)));
    mx = fmaxf(mx, m * s[e]);
  }
#pragma unroll
  for (int off = 32; off; off >>= 1) mx = fmaxf(mx, __shfl_xor(mx, off));
  mx = fmaxf(mx, 1e-30f);
  const float rq = 127.f / mx;
  if (lane == 0) sW[col] = mx / 127.f;
  char* op = outB + (size_t)col * K_DIM;
#pragma unroll
  for (int e = 0; e < 16; ++e) {
    const float sq = s[e] * rq;
    unsigned pk = ((unsigned)((int)rintf((float)c[e].x * sq)) & 0xFFu)
                | (((unsigned)((int)rintf((float)c[e].y * sq)) & 0xFFu) << 8)
                | (((unsigned)((int)rintf((float)c[e].z * sq)) & 0xFFu) << 16)
                | (((unsigned)((int)rintf((float)c[e].w * sq)) & 0xFFu) << 24);
    *(unsigned*)(op + e * 256 + lane * 4) = pk;
  }
}

__device__ __forceinline__ void gload16(const void* g, void* l) {
  __builtin_amdgcn_global_load_lds((const __attribute__((address_space(1))) void*)g,
                                   (__attribute__((address_space(3))) void*)l,
                                   16, 0, 0);
}

// === i8 GEMM: 256x128, 2 blocks/CU, 3-deep counted pipe, 32x32x32 MFMA,
//     fragment-contiguous LDS (conflict-free by construction, R8-validated) ===
#define BM 256
#define BN 128
#define BKB 64                     /* i8 elems (bytes) per K-tile */
#define NKT (K_DIM / BKB)          /* 64 */
#define TILES_M (M_DIM / BM)       /* 32 */
#define TILES_N (N_DIM / BN)       /* 86 */
#define NB2 (TILES_M * TILES_N)    /* 2752, %8==0 */
#define TSZA (BM * BKB)            /* 16384 B = 16 frags */
#define TSZB (BN * BKB)            /* 8192 B  = 8 frags */

#define VMCNT_(n) asm volatile("s_waitcnt vmcnt(" #n ")" ::: "memory")
#define VMCNT(n) VMCNT_(n)
#define BAR() __builtin_amdgcn_s_barrier()

__global__ __launch_bounds__(512, 4) void gemmq_kernel(
    const char* __restrict__ A,    // i8 [M][K]
    const char* __restrict__ B,    // i8 [N][K]
    const float* __restrict__ sA,  // per-row A scale
    const float* __restrict__ sW,  // per-col W scale
    const float* __restrict__ bias,
    float* __restrict__ out) {
  __shared__ __align__(16) char lA[3][TSZA];   // 48 KiB
  __shared__ __align__(16) char lB[3][TSZB];   // 24 KiB (72 total -> 2 blocks/CU)

  const int t = threadIdx.x;
  const int bid = blockIdx.x;
  const int wg = (bid & 7) * (NB2 / 8) + (bid >> 3);   // bijective XCD swizzle
  const int m0 = (wg / TILES_N) * BM;
  const int n0 = (wg % TILES_N) * BN;

  const int w = t >> 6;
  const int lane = t & 63;
  const int wm = w >> 1;   // 0..3  (64 rows each)
  const int wn = w & 1;    // 0..1  (64 cols each)
  const int l31 = lane & 31;
  const int l5 = lane >> 5;

  // Fragment-contiguous layout: one 32x32x32 frag = 1024 B, lane l holds
  // [row = rb*32 + (l&31)][k = ks*32 + (l>>5)*16 .. +16].
  // A-frag (rb,ks) at lA[rb*2048 + ks*1024]; B-frag g = rb*2+ks at lB[g*1024].
  // Staging: wave w stages A rb=w (ks=0,1) + B g=w. 3 gload16/thread/tile.
  // LDS dest wave-uniform; per-lane GLOBAL source does the transpose (m173).
  const size_t aoff = (size_t)(m0 + w * 32 + l31) * K_DIM + (unsigned)(l5 * 16);
  const size_t boff = (size_t)(n0 + (w >> 1) * 32 + l31) * K_DIM
                    + (unsigned)((w & 1) * 32 + l5 * 16);
  const int ldA0 = w * 2048;          // A ks=0 frag base
  const int ldA1 = w * 2048 + 1024;   // A ks=1
  const int ldB = w * 1024;           // B frag g=w

  i32x16 acc[2][2];                   // 64 AGPR
#pragma unroll
  for (int i = 0; i < 2; ++i)
#pragma unroll
    for (int j = 0; j < 2; ++j)
      acc[i][j] = (i32x16)(0);

#define STAGE(buf, kt)                                                        \
  do {                                                                        \
    gload16(A + aoff + (size_t)(kt) * BKB, &lA[buf][ldA0]);                   \
    gload16(A + aoff + (size_t)(kt) * BKB + 32, &lA[buf][ldA1]);              \
    gload16(B + boff + (size_t)(kt) * BKB, &lB[buf][ldB]);                    \
  } while (0)

  // reads: contiguous uniform + lane*16 -> zero bank conflicts by construction
#define TILE_CORE(CB)                                                         \
  i32x4 af[2][2], bq[2][2];                                                   \
  _Pragma("unroll") for (int i = 0; i < 2; ++i)                               \
  _Pragma("unroll") for (int ks = 0; ks < 2; ++ks)                            \
    af[i][ks] = *(const i32x4*)&lA[CB][(2 * wm + i) * 2048 + ks * 1024 + lane * 16]; \
  _Pragma("unroll") for (int j = 0; j < 2; ++j)                               \
  _Pragma("unroll") for (int ks = 0; ks < 2; ++ks)                            \
    bq[j][ks] = *(const i32x4*)&lB[CB][((2 * wn + j) * 2 + ks) * 1024 + lane * 16];

#define TILE_MMA()                                                            \
  __builtin_amdgcn_s_setprio(1);                                              \
  _Pragma("unroll") for (int ks = 0; ks < 2; ++ks)                            \
  _Pragma("unroll") for (int i = 0; i < 2; ++i)                               \
  _Pragma("unroll") for (int j = 0; j < 2; ++j)                               \
    acc[i][j] = __builtin_amdgcn_mfma_i32_32x32x32_i8(af[i][ks], bq[j][ks],   \
                                                      acc[i][j], 0, 0, 0);    \
  __builtin_amdgcn_s_setprio(0);

#define TILE(CB, SB, KT2)                                                     \
  {                                                                           \
    TILE_CORE(CB)                                                             \
    STAGE(SB, KT2);                                                           \
    TILE_MMA()                                                                \
    VMCNT(3);                                                                 \
    BAR();                                                                    \
  }

  // prologue: stage tiles 0,1; retire tile 0 (tile 1's 3 loads stay in flight)
  STAGE(0, 0);
  STAGE(1, 1);
  VMCNT(3);
  BAR();

  // main: 20 iters x 3 = tiles 0..59 (stages reach tile 61)
  for (int it = 0; it < 20; ++it) {
    const int k = 3 * it;
    TILE(0, 2, k + 2)
    TILE(1, 0, k + 3)
    TILE(2, 1, k + 4)
  }
  // peel: tile 60 (stages 62), 61 (stages 63), 62 (drain), 63
  TILE(0, 2, 62)
  TILE(1, 0, 63)
  {
    TILE_CORE(2)
    TILE_MMA()
    VMCNT(0);
    BAR();
  }
  {
    TILE_CORE(0)
    TILE_MMA()
  }

  // epilogue (R15-verified layout): col = lane&31,
  // row = (r&3) + 8*(r>>2) + 4*(lane>>5); nontemporal stores
  const int colb = n0 + wn * 64 + (lane & 31);
  const int rowb = m0 + wm * 64 + ((lane >> 5) << 2);
  float sar[2][16];
#pragma unroll
  for (int i = 0; i < 2; ++i)
#pragma unroll
    for (int r = 0; r < 16; ++r)
      sar[i][r] = sA[rowb + i * 32 + (r & 3) + 8 * (r >> 2)];
#pragma unroll
  for (int j = 0; j < 2; ++j) {
    const int col = colb + j * 32;
    const float sc2 = sW[col];
    const float bv = bias[col];
#pragma unroll
    for (int i = 0; i < 2; ++i) {
      const int rowf = rowb + i * 32;
#pragma unroll
      for (int r = 0; r < 16; ++r) {
        const int row = rowf + (r & 3) + 8 * (r >> 2);
        const float vout = (float)acc[i][j][r] * sar[i][r] * sc2 + bv;
        __builtin_nontemporal_store(vout, &out[(size_t)row * N_DIM + col]);
      }
    }
  }
#undef STAGE
#undef TILE_CORE
#undef TILE_MMA
#undef TILE
}

// ================= fallback: 128x128 inline-dequant GEMM =================
#define FBM 128
#define FBN 128
#define FBK 64
#define FNT_N 86
#define FNT_M 64
#define FNB (FNT_N * FNT_M)

__global__ __launch_bounds__(256, 2) void gemm_fb_kernel(
    const float* __restrict__ Ain, const int* __restrict__ Wcodes,
    const float* __restrict__ scales, const float* __restrict__ bias,
    float* __restrict__ out) {
  __shared__ unsigned short lsA[FBM * FBK];
  __shared__ unsigned short lsB[FBN * FBK];

  const int t = threadIdx.x;
  const int bid = blockIdx.x;
  const int wg = (bid & 7) * (FNB / 8) + (bid >> 3);
  const int m0 = (wg / FNT_N) * FBM;
  const int n0 = (wg % FNT_N) * FBN;

  const int w = t >> 6;
  const int lane = t & 63;
  const int wm = w >> 1, wn = w & 1;
  const int srow = t >> 3;
  const int sp = t & 7;
  const int skc = sp ^ (srow & 7);

  f32x4 acc[4][4];
#pragma unroll
  for (int i = 0; i < 4; ++i)
#pragma unroll
    for (int j = 0; j < 4; ++j) {
      f32x4 z = {0.f, 0.f, 0.f, 0.f};
      acc[i][j] = z;
    }

  for (int kt = 0; kt < K_DIM / FBK; ++kt) {
    const int kg = kt * FBK + skc * 8;
#pragma unroll
    for (int c = 0; c < 4; ++c) {
      const int arow = m0 + c * 32 + srow;
      const float* ap = Ain + (size_t)arow * K_DIM + kg;
      float4 a0 = *(const float4*)ap;
      float4 a1 = *(const float4*)(ap + 4);
      uint4 va;
      va.x = pk2(a0.x, a0.y); va.y = pk2(a0.z, a0.w);
      va.z = pk2(a1.x, a1.y); va.w = pk2(a1.z, a1.w);
      *(uint4*)&lsA[(c * 32 + srow) * FBK + sp * 8] = va;

      const int nrow = n0 + c * 32 + srow;
      const float s = scales[nrow * NGROUPS + (kg >> 7)];
      const int4* wp = (const int4*)(Wcodes + (size_t)nrow * K_DIM + kg);
      int4 c0 = wp[0], c1 = wp[1];
      uint4 vb;
      vb.x = pk2((float)c0.x * s, (float)c0.y * s);
      vb.y = pk2((float)c0.z * s, (float)c0.w * s);
      vb.z = pk2((float)c1.x * s, (float)c1.y * s);
      vb.w = pk2((float)c1.z * s, (float)c1.w * s);
      *(uint4*)&lsB[(c * 32 + srow) * FBK + sp * 8] = vb;
    }
    __syncthreads();
#pragma unroll
    for (int kk = 0; kk < 2; ++kk) {
      bf16x8 af[4], bfr[4];
#pragma unroll
      for (int i = 0; i < 4; ++i) {
        const int row = wm * 64 + i * 16 + (lane & 15);
        const int pg = (kk * 4 + (lane >> 4)) ^ (row & 7);
        af[i] = *(const bf16x8*)&lsA[row * FBK + pg * 8];
      }
#pragma unroll
      for (int j = 0; j < 4; ++j) {
        const int row = wn * 64 + j * 16 + (lane & 15);
        const int pg = (kk * 4 + (lane >> 4)) ^ (row & 7);
        bfr[j] = *(const bf16x8*)&lsB[row * FBK + pg * 8];
      }
#pragma unroll
      for (int i = 0; i < 4; ++i)
#pragma unroll
        for (int j = 0; j < 4; ++j)
          acc[i][j] = __builtin_amdgcn_mfma_f32_16x16x32_bf16(af[i], bfr[j], acc[i][j], 0, 0, 0);
    }
    __syncthreads();
  }

  const int colb = n0 + wn * 64 + (lane & 15);
  const int rowb = m0 + wm * 64 + ((lane >> 4) << 2);
#pragma unroll
  for (int j = 0; j < 4; ++j) {
    const int col = colb + j * 16;
    const float bv = bias[col];
#pragma unroll
    for (int i = 0; i < 4; ++i) {
      const int row = rowb + i * 16;
#pragma unroll
      for (int r = 0; r < 4; ++r)
        out[(size_t)(row + r) * N_DIM + col] = acc[i][j][r] + bv;
    }
  }
}

extern "C" void kernel_launch(void* const* d_in, const int* in_sizes, int n_in,
                              void* d_out, int out_size, void* d_ws, size_t ws_size,
                              hipStream_t stream) {
  const float* Ain = (const float*)d_in[0];
  const int* Wc = (const int*)d_in[1];
  const float* sc = (const float*)d_in[2];
  const float* bias = (const float*)d_in[3];
  float* out = (float*)d_out;

  const size_t offW = (size_t)M_DIM * K_DIM;            // A_i8: 32 MiB
  const size_t offSA = offW + (size_t)N_DIM * K_DIM;    // W_i8: 43 MiB
  const size_t offSW = offSA + (size_t)M_DIM * 4;       // sA: 32 KiB
  const size_t need = offSW + (size_t)N_DIM * 4;        // sW: 43 KiB

  if (ws_size >= need) {
    char* wsA = (char*)d_ws;
    char* wsB = (char*)d_ws + offW;
    float* sA = (float*)((char*)d_ws + offSA);
    float* sW = (float*)((char*)d_ws + offSW);
    quantA_kernel<<<M_DIM / 4, 256, 0, stream>>>(Ain, wsA, sA);
    quantW_kernel<<<N_DIM / 4, 256, 0, stream>>>(Wc, sc, wsB, sW);
    gemmq_kernel<<<NB2, 512, 0, stream>>>(wsA, wsB, sA, sW, bias, out);
  } else {
    gemm_fb_kernel<<<FNB, 256, 0, stream>>>(Ain, Wc, sc, bias, out);
  }
}

// Round 19
// 469.755 us; speedup vs baseline: 1.3639x; 1.3639x over previous
//
#include <hip/hip_runtime.h>
#include <hip/hip_bf16.h>
#include <cstdint>

#define M_DIM 8192
#define K_DIM 4096
#define N_DIM 11008
#define NGROUPS 32

typedef __attribute__((ext_vector_type(4))) float f32x4;
typedef __attribute__((ext_vector_type(4))) int i32x4;
typedef __attribute__((ext_vector_type(8))) __bf16 bf16x8;

__device__ __forceinline__ unsigned int f2bf(float f) {
  unsigned int u = __builtin_bit_cast(unsigned int, f);
  return (u + 0x7FFFu + ((u >> 16) & 1u)) >> 16;
}
__device__ __forceinline__ unsigned int pk2(float lo, float hi) {
  return f2bf(lo) | (f2bf(hi) << 16);
}

// ---- prepass A: per-row int8 quantization, single-pass (regs), nt loads ----
__global__ __launch_bounds__(256) void quantA_kernel(const float* __restrict__ in,
                                                     char* __restrict__ outA,
                                                     float* __restrict__ sA) {
  const int row = blockIdx.x * 4 + (threadIdx.x >> 6);
  const int lane = threadIdx.x & 63;
  const f32x4* p4 = (const f32x4*)(in + (size_t)row * K_DIM);
  f32x4 v[16];
#pragma unroll
  for (int e = 0; e < 16; ++e)
    v[e] = __builtin_nontemporal_load(&p4[e * 64 + lane]);
  float mx = 0.f;
#pragma unroll
  for (int e = 0; e < 16; ++e)
    mx = fmaxf(mx, fmaxf(fmaxf(fabsf(v[e].x), fabsf(v[e].y)),
                         fmaxf(fabsf(v[e].z), fabsf(v[e].w))));
#pragma unroll
  for (int off = 32; off; off >>= 1) mx = fmaxf(mx, __shfl_xor(mx, off));
  mx = fmaxf(mx, 1e-30f);
  const float rq = 127.f / mx;
  if (lane == 0) sA[row] = mx / 127.f;
  char* op = outA + (size_t)row * K_DIM;
#pragma unroll
  for (int e = 0; e < 16; ++e) {
    unsigned pk = ((unsigned)((int)rintf(v[e].x * rq)) & 0xFFu)
                | (((unsigned)((int)rintf(v[e].y * rq)) & 0xFFu) << 8)
                | (((unsigned)((int)rintf(v[e].z * rq)) & 0xFFu) << 16)
                | (((unsigned)((int)rintf(v[e].w * rq)) & 0xFFu) << 24);
    *(unsigned*)(op + e * 256 + lane * 4) = pk;
  }
}

// ---- prepass W: per-column int8 re-quant, single-pass (regs), nt loads ----
__global__ __launch_bounds__(256) void quantW_kernel(const int* __restrict__ wc,
                                                     const float* __restrict__ sc,
                                                     char* __restrict__ outB,
                                                     float* __restrict__ sW) {
  const int col = blockIdx.x * 4 + (threadIdx.x >> 6);
  const int lane = threadIdx.x & 63;
  const i32x4* p = (const i32x4*)(wc + (size_t)col * K_DIM);
  const float* scp = sc + col * NGROUPS;
  i32x4 c[16];
  float s[16];
#pragma unroll
  for (int e = 0; e < 16; ++e) {
    c[e] = __builtin_nontemporal_load(&p[e * 64 + lane]);
    s[e] = scp[e * 2 + (lane >> 5)];
  }
  float mx = 0.f;
#pragma unroll
  for (int e = 0; e < 16; ++e) {
    float m = fmaxf(fmaxf(fabsf((float)c[e].x), fabsf((float)c[e].y)),
                    fmaxf(fabsf((float)c[e].z), fabsf((float)c[e].w)));
    mx = fmaxf(mx, m * s[e]);
  }
#pragma unroll
  for (int off = 32; off; off >>= 1) mx = fmaxf(mx, __shfl_xor(mx, off));
  mx = fmaxf(mx, 1e-30f);
  const float rq = 127.f / mx;
  if (lane == 0) sW[col] = mx / 127.f;
  char* op = outB + (size_t)col * K_DIM;
#pragma unroll
  for (int e = 0; e < 16; ++e) {
    const float sq = s[e] * rq;
    unsigned pk = ((unsigned)((int)rintf((float)c[e].x * sq)) & 0xFFu)
                | (((unsigned)((int)rintf((float)c[e].y * sq)) & 0xFFu) << 8)
                | (((unsigned)((int)rintf((float)c[e].z * sq)) & 0xFFu) << 16)
                | (((unsigned)((int)rintf((float)c[e].w * sq)) & 0xFFu) << 24);
    *(unsigned*)(op + e * 256 + lane * 4) = pk;
  }
}

__device__ __forceinline__ void gload16(const void* g, void* l) {
  __builtin_amdgcn_global_load_lds((const __attribute__((address_space(1))) void*)g,
                                   (__attribute__((address_space(3))) void*)l,
                                   16, 0, 0);
}

// === i8 GEMM (R14/R17-proven): 256x128, 2 blocks/CU, 3-deep counted pipe,
//     16x16x64 MFMA (0 bank conflicts), nontemporal output stores ===
#define BM 256
#define BN 128
#define BKB 64                     /* i8 elems (bytes) per K-tile */
#define NKT (K_DIM / BKB)          /* 64 */
#define TILES_M (M_DIM / BM)       /* 32 */
#define TILES_N (N_DIM / BN)       /* 86 */
#define NB2 (TILES_M * TILES_N)    /* 2752, %8==0 */
#define TSZA (BM * BKB)            /* 16384 B */
#define TSZB (BN * BKB)            /* 8192 B */

#define VMCNT_(n) asm volatile("s_waitcnt vmcnt(" #n ")" ::: "memory")
#define VMCNT(n) VMCNT_(n)
#define BAR() __builtin_amdgcn_s_barrier()

__global__ __launch_bounds__(512, 4) void gemmq_kernel(
    const char* __restrict__ A,    // i8 [M][K]
    const char* __restrict__ B,    // i8 [N][K]
    const float* __restrict__ sA,  // per-row A scale
    const float* __restrict__ sW,  // per-col W scale
    const float* __restrict__ bias,
    float* __restrict__ out) {
  __shared__ __align__(16) char lA[3][TSZA];   // 48 KiB
  __shared__ __align__(16) char lB[3][TSZB];   // 24 KiB (72 total -> 2 blocks/CU)

  const int t = threadIdx.x;
  const int bid = blockIdx.x;
  const int wg = (bid & 7) * (NB2 / 8) + (bid >> 3);   // bijective XCD swizzle
  const int m0 = (wg / TILES_N) * BM;
  const int n0 = (wg % TILES_N) * BN;

  const int w = t >> 6;
  const int lane = t & 63;
  const int wm = w >> 1;   // 0..3  (64 rows each)
  const int wn = w & 1;    // 0..1  (64 cols each)

  // staging (R14-verified): rows are 64 B = 4 granules of 16 B.
  const int ra0 = w * 32 + (lane >> 2);
  const int ra1 = ra0 + 16;
  const int rb = w * 16 + (lane >> 2);
  const int pgs = lane & 3;
  const size_t aoff0 = (size_t)(m0 + ra0) * K_DIM + (unsigned)(pgs ^ ((ra0 >> 1) & 3)) * 16;
  const size_t aoff1 = (size_t)(m0 + ra1) * K_DIM + (unsigned)(pgs ^ ((ra1 >> 1) & 3)) * 16;
  const size_t boff = (size_t)(n0 + rb) * K_DIM + (unsigned)(pgs ^ ((rb >> 1) & 3)) * 16;
  const int ldA0 = w * 2048;
  const int ldA1 = w * 2048 + 1024;
  const int ldB = w * 1024;

  i32x4 acc[4][4];                    // 64 AGPR
#pragma unroll
  for (int i = 0; i < 4; ++i)
#pragma unroll
    for (int j = 0; j < 4; ++j) {
      i32x4 z = {0, 0, 0, 0};
      acc[i][j] = z;
    }

#define STAGE(buf, kt)                                                        \
  do {                                                                        \
    gload16(A + aoff0 + (size_t)(kt) * BKB, &lA[buf][ldA0]);                  \
    gload16(A + aoff1 + (size_t)(kt) * BKB, &lA[buf][ldA1]);                  \
    gload16(B + boff + (size_t)(kt) * BKB, &lB[buf][ldB]);                    \
  } while (0)

#define TILE_CORE(CB)                                                         \
  i32x4 af[4], bq[4];                                                         \
  _Pragma("unroll") for (int i = 0; i < 4; ++i) {                             \
    const int row = wm * 64 + i * 16 + (lane & 15);                           \
    const int pg = (lane >> 4) ^ ((row >> 1) & 3);                            \
    af[i] = *(const i32x4*)&lA[CB][row * 64 + pg * 16];                       \
  }                                                                           \
  _Pragma("unroll") for (int j = 0; j < 4; ++j) {                             \
    const int row = wn * 64 + j * 16 + (lane & 15);                           \
    const int pg = (lane >> 4) ^ ((row >> 1) & 3);                            \
    bq[j] = *(const i32x4*)&lB[CB][row * 64 + pg * 16];                       \
  }

#define TILE_MMA()                                                            \
  __builtin_amdgcn_s_setprio(1);                                              \
  _Pragma("unroll") for (int i = 0; i < 4; ++i)                               \
  _Pragma("unroll") for (int j = 0; j < 4; ++j)                               \
    acc[i][j] = __builtin_amdgcn_mfma_i32_16x16x64_i8(af[i], bq[j],           \
                                                      acc[i][j], 0, 0, 0);    \
  __builtin_amdgcn_s_setprio(0);

#define TILE(CB, SB, KT2)                                                     \
  {                                                                           \
    TILE_CORE(CB)                                                             \
    STAGE(SB, KT2);                                                           \
    TILE_MMA()                                                                \
    VMCNT(3);                                                                 \
    BAR();                                                                    \
  }

  // prologue: stage tiles 0,1; retire tile 0 (tile 1's 3 loads stay in flight)
  STAGE(0, 0);
  STAGE(1, 1);
  VMCNT(3);
  BAR();

  // main: 20 iters x 3 = tiles 0..59 (stages reach tile 61)
  for (int it = 0; it < 20; ++it) {
    const int k = 3 * it;
    TILE(0, 2, k + 2)
    TILE(1, 0, k + 3)
    TILE(2, 1, k + 4)
  }
  // peel: tile 60 (stages 62), 61 (stages 63), 62 (drain), 63
  TILE(0, 2, 62)
  TILE(1, 0, 63)
  {
    TILE_CORE(2)
    TILE_MMA()
    VMCNT(0);
    BAR();
  }
  {
    TILE_CORE(0)
    TILE_MMA()
  }

  // epilogue: C col = lane&15, row = (lane>>4)*4 + r; nontemporal stores
  const int colb = n0 + wn * 64 + (lane & 15);
  const int rowb = m0 + wm * 64 + ((lane >> 4) << 2);
  float sar[4][4];
#pragma unroll
  for (int ai = 0; ai < 4; ++ai)
#pragma unroll
    for (int r = 0; r < 4; ++r)
      sar[ai][r] = sA[rowb + ai * 16 + r];
#pragma unroll
  for (int j = 0; j < 4; ++j) {
    const int col = colb + j * 16;
    const float sc2 = sW[col];
    const float bv = bias[col];
#pragma unroll
    for (int ai = 0; ai < 4; ++ai) {
      const int row = rowb + ai * 16;
#pragma unroll
      for (int r = 0; r < 4; ++r) {
        const float vout = (float)acc[ai][j][r] * sar[ai][r] * sc2 + bv;
        __builtin_nontemporal_store(vout, &out[(size_t)(row + r) * N_DIM + col]);
      }
    }
  }
#undef STAGE
#undef TILE_CORE
#undef TILE_MMA
#undef TILE
}

// ================= fallback: 128x128 inline-dequant GEMM =================
#define FBM 128
#define FBN 128
#define FBK 64
#define FNT_N 86
#define FNT_M 64
#define FNB (FNT_N * FNT_M)

__global__ __launch_bounds__(256, 2) void gemm_fb_kernel(
    const float* __restrict__ Ain, const int* __restrict__ Wcodes,
    const float* __restrict__ scales, const float* __restrict__ bias,
    float* __restrict__ out) {
  __shared__ unsigned short lsA[FBM * FBK];
  __shared__ unsigned short lsB[FBN * FBK];

  const int t = threadIdx.x;
  const int bid = blockIdx.x;
  const int wg = (bid & 7) * (FNB / 8) + (bid >> 3);
  const int m0 = (wg / FNT_N) * FBM;
  const int n0 = (wg % FNT_N) * FBN;

  const int w = t >> 6;
  const int lane = t & 63;
  const int wm = w >> 1, wn = w & 1;
  const int srow = t >> 3;
  const int sp = t & 7;
  const int skc = sp ^ (srow & 7);

  f32x4 acc[4][4];
#pragma unroll
  for (int i = 0; i < 4; ++i)
#pragma unroll
    for (int j = 0; j < 4; ++j) {
      f32x4 z = {0.f, 0.f, 0.f, 0.f};
      acc[i][j] = z;
    }

  for (int kt = 0; kt < K_DIM / FBK; ++kt) {
    const int kg = kt * FBK + skc * 8;
#pragma unroll
    for (int c = 0; c < 4; ++c) {
      const int arow = m0 + c * 32 + srow;
      const float* ap = Ain + (size_t)arow * K_DIM + kg;
      float4 a0 = *(const float4*)ap;
      float4 a1 = *(const float4*)(ap + 4);
      uint4 va;
      va.x = pk2(a0.x, a0.y); va.y = pk2(a0.z, a0.w);
      va.z = pk2(a1.x, a1.y); va.w = pk2(a1.z, a1.w);
      *(uint4*)&lsA[(c * 32 + srow) * FBK + sp * 8] = va;

      const int nrow = n0 + c * 32 + srow;
      const float s = scales[nrow * NGROUPS + (kg >> 7)];
      const int4* wp = (const int4*)(Wcodes + (size_t)nrow * K_DIM + kg);
      int4 c0 = wp[0], c1 = wp[1];
      uint4 vb;
      vb.x = pk2((float)c0.x * s, (float)c0.y * s);
      vb.y = pk2((float)c0.z * s, (float)c0.w * s);
      vb.z = pk2((float)c1.x * s, (float)c1.y * s);
      vb.w = pk2((float)c1.z * s, (float)c1.w * s);
      *(uint4*)&lsB[(c * 32 + srow) * FBK + sp * 8] = vb;
    }
    __syncthreads();
#pragma unroll
    for (int kk = 0; kk < 2; ++kk) {
      bf16x8 af[4], bfr[4];
#pragma unroll
      for (int i = 0; i < 4; ++i) {
        const int row = wm * 64 + i * 16 + (lane & 15);
        const int pg = (kk * 4 + (lane >> 4)) ^ (row & 7);
        af[i] = *(const bf16x8*)&lsA[row * FBK + pg * 8];
      }
#pragma unroll
      for (int j = 0; j < 4; ++j) {
        const int row = wn * 64 + j * 16 + (lane & 15);
        const int pg = (kk * 4 + (lane >> 4)) ^ (row & 7);
        bfr[j] = *(const bf16x8*)&lsB[row * FBK + pg * 8];
      }
#pragma unroll
      for (int i = 0; i < 4; ++i)
#pragma unroll
        for (int j = 0; j < 4; ++j)
          acc[i][j] = __builtin_amdgcn_mfma_f32_16x16x32_bf16(af[i], bfr[j], acc[i][j], 0, 0, 0);
    }
    __syncthreads();
  }

  const int colb = n0 + wn * 64 + (lane & 15);
  const int rowb = m0 + wm * 64 + ((lane >> 4) << 2);
#pragma unroll
  for (int j = 0; j < 4; ++j) {
    const int col = colb + j * 16;
    const float bv = bias[col];
#pragma unroll
    for (int i = 0; i < 4; ++i) {
      const int row = rowb + i * 16;
#pragma unroll
      for (int r = 0; r < 4; ++r)
        out[(size_t)(row + r) * N_DIM + col] = acc[i][j][r] + bv;
    }
  }
}

extern "C" void kernel_launch(void* const* d_in, const int* in_sizes, int n_in,
                              void* d_out, int out_size, void* d_ws, size_t ws_size,
                              hipStream_t stream) {
  const float* Ain = (const float*)d_in[0];
  const int* Wc = (const int*)d_in[1];
  const float* sc = (const float*)d_in[2];
  const float* bias = (const float*)d_in[3];
  float* out = (float*)d_out;

  const size_t offW = (size_t)M_DIM * K_DIM;            // A_i8: 32 MiB
  const size_t offSA = offW + (size_t)N_DIM * K_DIM;    // W_i8: 43 MiB
  const size_t offSW = offSA + (size_t)M_DIM * 4;       // sA: 32 KiB
  const size_t need = offSW + (size_t)N_DIM * 4;        // sW: 43 KiB

  if (ws_size >= need) {
    char* wsA = (char*)d_ws;
    char* wsB = (char*)d_ws + offW;
    float* sA = (float*)((char*)d_ws + offSA);
    float* sW = (float*)((char*)d_ws + offSW);
    quantA_kernel<<<M_DIM / 4, 256, 0, stream>>>(Ain, wsA, sA);
    quantW_kernel<<<N_DIM / 4, 256, 0, stream>>>(Wc, sc, wsB, sW);
    gemmq_kernel<<<NB2, 512, 0, stream>>>(wsA, wsB, sA, sW, bias, out);
  } else {
    gemm_fb_kernel<<<FNB, 256, 0, stream>>>(Ain, Wc, sc, bias, out);
  }
}